// Round 1
// baseline (411.463 us; speedup 1.0000x reference)
//
#include <hip/hip_runtime.h>
#include <math.h>

#define CC 64
#define HWN 4096
#define QB 32
#define KT 64
#define LDK 68   // bg tile row stride: 16B-aligned rows; col reads land 2-way banks with stride-16 c-tile
#define LDQ 34

// ---------------- norms: sb[b,k]=1/max(||bg[:,k]||,eps), sf[b,q] likewise ----------------
__global__ void norms_kernel(const float* __restrict__ bg,
                             const float* __restrict__ fg,
                             float* __restrict__ sb,
                             float* __restrict__ sf) {
  int tid = blockIdx.x * 256 + threadIdx.x;   // 0..32767
  int which = tid >> 14;                      // 0: background->sb, 1: foreground->sf
  int idx = tid & 16383;                      // b*4096 + pos
  int b = idx >> 12, pos = idx & 4095;
  const float* src = which ? fg : bg;
  const float* col = src + (size_t)b * CC * HWN + pos;
  float ss = 0.f;
#pragma unroll
  for (int c = 0; c < CC; ++c) {
    float v = col[(size_t)c * HWN];
    ss = fmaf(v, v, ss);
  }
  float n = fmaxf(sqrtf(ss), 1e-12f);
  float s = 1.0f / n;
  if (which) sf[idx] = s; else sb[idx] = s;
}

// ---------------- flash-style attention, fp32 vector ----------------
__global__ __launch_bounds__(256) void attn_kernel(
    const float* __restrict__ bg, const float* __restrict__ fg,
    const float* __restrict__ mask, const float* __restrict__ sb,
    const float* __restrict__ sf, float* __restrict__ out) {
  __shared__ __align__(16) float bg_lds[CC][LDK];   // [c][k] chunk
  __shared__ __align__(16) float fg_lds[CC][LDQ];   // [c][q] tile (whole kernel)
  __shared__ __align__(16) float p_lds[KT][LDQ];    // [k][q] probabilities
  __shared__ float sf_lds[QB];

  const int b = blockIdx.y;
  const int q0 = blockIdx.x * QB;
  const int tid = threadIdx.x;
  const float* bgB = bg + (size_t)b * CC * HWN;
  const float* fgB = fg + (size_t)b * CC * HWN;

  // stage fg tile + sf scales (once); coalesced over q
  {
    int q = tid & 31;
    int c0 = (tid >> 5) * 8;
#pragma unroll
    for (int i = 0; i < 8; ++i)
      fg_lds[c0 + i][q] = fgB[(size_t)(c0 + i) * HWN + q0 + q];
    if (tid < QB) sf_lds[tid] = sf[b * HWN + q0 + tid];
  }

  const int tk = tid & 15;   // score phase: keys k = 4*tk+i ; PV phase: channels c = tk+16*i
  const int tq = tid >> 4;   // queries q = 2*tq+j  (tq in 0..15; same split both phases)

  float m_run[2] = {-1e30f, -1e30f};
  float l_run[2] = {0.f, 0.f};
  float O[4][2] = {{0.f,0.f},{0.f,0.f},{0.f,0.f},{0.f,0.f}};

  for (int kb = 0; kb < HWN; kb += KT) {
    __syncthreads();   // protect bg_lds/p_lds from previous chunk (and fg staging on iter 0)

    // stage bg chunk [64c][64k]: fully-coalesced float4 reads, 16B LDS writes
    {
      int k4 = tid & 15, c16 = tid >> 4;
#pragma unroll
      for (int j = 0; j < 4; ++j) {
        int c = c16 + j * 16;
        float4 v = *(const float4*)(bgB + (size_t)c * HWN + kb + k4 * 4);
        *(float4*)&bg_lds[c][k4 * 4] = v;
      }
    }
    __syncthreads();

    // ---- scores: 4k x 2q register tile, inner dim c=64 ----
    float acc[4][2] = {{0.f,0.f},{0.f,0.f},{0.f,0.f},{0.f,0.f}};
#pragma unroll 8
    for (int c = 0; c < CC; ++c) {
      float4 bv = *(const float4*)&bg_lds[c][tk * 4];  // 16 addrs / 8 banks = 2-way (free)
      float f0 = fg_lds[c][2 * tq];                    // broadcast
      float f1 = fg_lds[c][2 * tq + 1];
      acc[0][0] = fmaf(bv.x, f0, acc[0][0]); acc[0][1] = fmaf(bv.x, f1, acc[0][1]);
      acc[1][0] = fmaf(bv.y, f0, acc[1][0]); acc[1][1] = fmaf(bv.y, f1, acc[1][1]);
      acc[2][0] = fmaf(bv.z, f0, acc[2][0]); acc[2][1] = fmaf(bv.z, f1, acc[2][1]);
      acc[3][0] = fmaf(bv.w, f0, acc[3][0]); acc[3][1] = fmaf(bv.w, f1, acc[3][1]);
    }

    // ---- scale by sb[k]*sf[q], online softmax over k (shfl over the 16 tk-lanes) ----
    float4 sbv = *(const float4*)(sb + b * HWN + kb + tk * 4);
    float sb4[4] = {sbv.x, sbv.y, sbv.z, sbv.w};
    float p[4][2];
#pragma unroll
    for (int j = 0; j < 2; ++j) {
      float sfv = sf_lds[2 * tq + j];
      float s0 = acc[0][j] * sb4[0] * sfv;
      float s1 = acc[1][j] * sb4[1] * sfv;
      float s2 = acc[2][j] * sb4[2] * sfv;
      float s3 = acc[3][j] * sb4[3] * sfv;
      float mc = fmaxf(fmaxf(s0, s1), fmaxf(s2, s3));
#pragma unroll
      for (int off = 1; off <= 8; off <<= 1)
        mc = fmaxf(mc, __shfl_xor(mc, off, 64));
      float mnew = fmaxf(m_run[j], mc);
      float alpha = __expf(m_run[j] - mnew);   // first chunk: exp(-1e30-x)=0, no NaN
      float p0 = __expf(s0 - mnew), p1 = __expf(s1 - mnew);
      float p2 = __expf(s2 - mnew), p3 = __expf(s3 - mnew);
      float ps = (p0 + p1) + (p2 + p3);
#pragma unroll
      for (int off = 1; off <= 8; off <<= 1)
        ps += __shfl_xor(ps, off, 64);
      l_run[j] = l_run[j] * alpha + ps;
      m_run[j] = mnew;
      O[0][j] *= alpha; O[1][j] *= alpha; O[2][j] *= alpha; O[3][j] *= alpha;
      p[0][j] = p0; p[1][j] = p1; p[2][j] = p2; p[3][j] = p3;
    }
#pragma unroll
    for (int i = 0; i < 4; ++i) {
      float2 pw = make_float2(p[i][0], p[i][1]);
      *(float2*)&p_lds[4 * tk + i][2 * tq] = pw;   // 4-way banks, cheap
    }
    __syncthreads();

    // ---- PV: O[c,q] += bg[c,k] * p[k,q]; c-tile strided by 16 (2-way banks) ----
#pragma unroll 8
    for (int k = 0; k < KT; ++k) {
      float2 pv = *(const float2*)&p_lds[k][2 * tq];   // broadcast
#pragma unroll
      for (int i = 0; i < 4; ++i) {
        float bv = bg_lds[tk + 16 * i][k];             // Δrow=68 -> 8 banks x 2 addrs
        O[i][0] = fmaf(bv, pv.x, O[i][0]);
        O[i][1] = fmaf(bv, pv.y, O[i][1]);
      }
    }
  }

  // ---- epilogue: blend with mask, write ----
#pragma unroll
  for (int j = 0; j < 2; ++j) {
    int q = q0 + 2 * tq + j;
    float mv = mask[b * HWN + q];
    float invl = 1.0f / l_run[j];
#pragma unroll
    for (int i = 0; i < 4; ++i) {
      int c = tk + 16 * i;
      float att = O[i][j] * invl;
      float fgv = fg_lds[c][2 * tq + j];
      out[(size_t)b * CC * HWN + (size_t)c * HWN + q] = fgv * (1.0f - mv) + att * mv;
    }
  }
}

extern "C" void kernel_launch(void* const* d_in, const int* in_sizes, int n_in,
                              void* d_out, int out_size, void* d_ws, size_t ws_size,
                              hipStream_t stream) {
  const float* background = (const float*)d_in[0];
  const float* foreground = (const float*)d_in[1];
  const float* mask       = (const float*)d_in[2];
  float* out = (float*)d_out;
  // ws: sb[4*4096] fp32, then sf[4*4096] fp32  (128 KiB)
  float* sb = (float*)d_ws;
  float* sf = sb + 4 * HWN;
  norms_kernel<<<128, 256, 0, stream>>>(background, foreground, sb, sf);
  attn_kernel<<<dim3(128, 4), 256, 0, stream>>>(background, foreground, mask, sb, sf, out);
}

// Round 2
// 153.190 us; speedup vs baseline: 2.6860x; 2.6860x over previous
//
#include <hip/hip_runtime.h>
#include <math.h>

#define CC 64
#define HWN 4096
#define QB 32
#define KSPLIT 4
#define KT 32
#define NCHUNK (HWN / KSPLIT / KT)   // 32

typedef __attribute__((ext_vector_type(8))) short bf16x8;
typedef __attribute__((ext_vector_type(4))) float f32x4;

// LDS carve (bytes)
#define OFF_BGN 0        // ushort [4ks][64c][40k]   (raw bg, PV A-operand)
#define OFF_BGT 20480    // ushort [4ks][32k][72c]   (bg*sb, score A-operand)
#define OFF_FGT 38912    // ushort [32q][72c]        (fg*sf, score B-operand)
#define OFF_P   43520    // ushort [8w][16q][40k]    (P, PV B-operand)
#define SMEM_BYTES 53760

static __device__ __forceinline__ unsigned int f2bf(float x) {
  union { float f; unsigned int u; } v; v.f = x;
  unsigned int r = v.u + 0x7fffu + ((v.u >> 16) & 1u);   // RNE
  return r >> 16;
}

// ---------------- norms: sb[b,k]=1/max(||bg[:,k]||,eps), sf likewise ----------------
__global__ void norms_kernel(const float* __restrict__ bg,
                             const float* __restrict__ fg,
                             float* __restrict__ sb,
                             float* __restrict__ sf) {
  int tid = blockIdx.x * 128 + threadIdx.x;   // 0..32767
  int which = tid >> 14;
  int idx = tid & 16383;
  int b = idx >> 12, pos = idx & 4095;
  const float* col = (which ? fg : bg) + (size_t)b * CC * HWN + pos;
  float ss = 0.f;
#pragma unroll
  for (int c = 0; c < CC; ++c) {
    float v = col[(size_t)c * HWN];
    ss = fmaf(v, v, ss);
  }
  float s = 1.0f / fmaxf(sqrtf(ss), 1e-12f);
  if (which) sf[idx] = s; else sb[idx] = s;
}

// ---------------- bf16 MFMA flash attention, in-block K-split=4 ----------------
__global__ __launch_bounds__(512, 4) void attn_kernel(
    const float* __restrict__ bg, const float* __restrict__ fg,
    const float* __restrict__ mask, const float* __restrict__ sb,
    const float* __restrict__ sf, float* __restrict__ out) {
  __shared__ __align__(16) char smem[SMEM_BYTES];
  unsigned short* bgn = (unsigned short*)(smem + OFF_BGN);
  unsigned short* bgt = (unsigned short*)(smem + OFF_BGT);
  unsigned short* fgt = (unsigned short*)(smem + OFF_FGT);
  unsigned short* pls = (unsigned short*)(smem + OFF_P);

  const int b = blockIdx.y;
  const int q0 = blockIdx.x * QB;
  const int tid = threadIdx.x;
  const int lane = tid & 63;
  const int w = tid >> 6;        // 0..7
  const int qg = w & 1;          // q-group (16 q each)
  const int ks = w >> 1;         // K-split 0..3
  const int m16 = lane & 15;
  const int quad = lane >> 4;

  const float* bgB = bg + (size_t)b * CC * HWN;
  const float* fgB = fg + (size_t)b * CC * HWN;
  const float* sbB = sb + b * HWN;
  const float* sfB = sf + b * HWN;

  // ---- stage fg_t[q][c] (sf folded), once ----
  {
    int q = tid & 31;
    int cg = tid >> 5;           // 0..15, owns c = 4cg..4cg+3
    float sfv = sfB[q0 + q];
    float v0 = fgB[(size_t)(4 * cg + 0) * HWN + q0 + q] * sfv;
    float v1 = fgB[(size_t)(4 * cg + 1) * HWN + q0 + q] * sfv;
    float v2 = fgB[(size_t)(4 * cg + 2) * HWN + q0 + q] * sfv;
    float v3 = fgB[(size_t)(4 * cg + 3) * HWN + q0 + q] * sfv;
    *(unsigned int*)&fgt[q * 72 + 4 * cg]     = f2bf(v0) | (f2bf(v1) << 16);
    *(unsigned int*)&fgt[q * 72 + 4 * cg + 2] = f2bf(v2) | (f2bf(v3) << 16);
  }
  __syncthreads();

  // score B-fragments (fg is kernel-constant): B[k=c][n=q], q=lane&15, c=quad*8+j
  bf16x8 Bf0 = *(const bf16x8*)&fgt[(qg * 16 + m16) * 72 + quad * 8];
  bf16x8 Bf1 = *(const bf16x8*)&fgt[(qg * 16 + m16) * 72 + 32 + quad * 8];

  // staging ids within the 128-thread ks-group
  const int t128 = (qg << 6) | lane;
  const int k4 = (t128 & 7) * 4;       // key offset 0..28
  const int cpair = t128 >> 3;         // 0..15

  float m_run = -1e30f, l_run = 0.f;
  f32x4 O[4] = {{0,0,0,0},{0,0,0,0},{0,0,0,0},{0,0,0,0}};

  for (int it = 0; it < NCHUNK; ++it) {
    const int kb = ks * (HWN / KSPLIT) + it * KT;
    __syncthreads();   // previous chunk's PV reads done before restaging

    // ---- stage bg chunk: natural [c][k] (raw) + transposed [k][c] (*sb) ----
    float4 sbv = *(const float4*)(sbB + kb + k4);
    const float sbe[4] = {sbv.x, sbv.y, sbv.z, sbv.w};
#pragma unroll
    for (int p = 0; p < 2; ++p) {
      int c0 = 2 * cpair + 32 * p;
      float4 a = *(const float4*)(bgB + (size_t)c0 * HWN + kb + k4);
      float4 bb = *(const float4*)(bgB + (size_t)(c0 + 1) * HWN + kb + k4);
      unsigned int n0 = f2bf(a.x) | (f2bf(a.y) << 16);
      unsigned int n1 = f2bf(a.z) | (f2bf(a.w) << 16);
      *(uint2*)&bgn[(ks * 64 + c0) * 40 + k4] = make_uint2(n0, n1);
      unsigned int n2 = f2bf(bb.x) | (f2bf(bb.y) << 16);
      unsigned int n3 = f2bf(bb.z) | (f2bf(bb.w) << 16);
      *(uint2*)&bgn[(ks * 64 + c0 + 1) * 40 + k4] = make_uint2(n2, n3);
      const float av[4] = {a.x, a.y, a.z, a.w};
      const float bv[4] = {bb.x, bb.y, bb.z, bb.w};
#pragma unroll
      for (int e = 0; e < 4; ++e) {
        unsigned int pk = f2bf(av[e] * sbe[e]) | (f2bf(bv[e] * sbe[e]) << 16);
        *(unsigned int*)&bgt[(ks * 32 + k4 + e) * 72 + c0] = pk;
      }
    }
    __syncthreads();

    // ---- scores: S[k 32][q 16] = (bg*sb)^T · (fg*sf) ----
    f32x4 S[2];
#pragma unroll
    for (int i = 0; i < 2; ++i) {
      f32x4 acc = {0, 0, 0, 0};
      bf16x8 A0 = *(const bf16x8*)&bgt[(ks * 32 + 16 * i + m16) * 72 + quad * 8];
      acc = __builtin_amdgcn_mfma_f32_16x16x32_bf16(A0, Bf0, acc, 0, 0, 0);
      bf16x8 A1 = *(const bf16x8*)&bgt[(ks * 32 + 16 * i + m16) * 72 + 32 + quad * 8];
      acc = __builtin_amdgcn_mfma_f32_16x16x32_bf16(A1, Bf1, acc, 0, 0, 0);
      S[i] = acc;
    }

    // ---- online softmax over the 32 chunk keys (regs + quads) ----
    float mc = -1e30f;
#pragma unroll
    for (int i = 0; i < 2; ++i)
#pragma unroll
      for (int r = 0; r < 4; ++r) mc = fmaxf(mc, S[i][r]);
    mc = fmaxf(mc, __shfl_xor(mc, 16, 64));
    mc = fmaxf(mc, __shfl_xor(mc, 32, 64));
    float mnew = fmaxf(m_run, mc);
    float alpha = __expf(m_run - mnew);
    float pe[2][4];
    float ps = 0.f;
#pragma unroll
    for (int i = 0; i < 2; ++i)
#pragma unroll
      for (int r = 0; r < 4; ++r) { pe[i][r] = __expf(S[i][r] - mnew); ps += pe[i][r]; }
    ps += __shfl_xor(ps, 16, 64);
    ps += __shfl_xor(ps, 32, 64);
    l_run = l_run * alpha + ps;
    m_run = mnew;
#pragma unroll
    for (int t = 0; t < 4; ++t)
#pragma unroll
      for (int r = 0; r < 4; ++r) O[t][r] *= alpha;

    // ---- P -> LDS [q][k] (bf16), per-wave region; 4 consecutive k per b64 ----
#pragma unroll
    for (int i = 0; i < 2; ++i) {
      unsigned int p0 = f2bf(pe[i][0]) | (f2bf(pe[i][1]) << 16);
      unsigned int p1 = f2bf(pe[i][2]) | (f2bf(pe[i][3]) << 16);
      *(uint2*)&pls[(w * 16 + m16) * 40 + 16 * i + quad * 4] = make_uint2(p0, p1);
    }

    // ---- PV: O[c][q] += bg[c][k] · P[k][q]  (contraction k = 32, one step) ----
    bf16x8 Pf = *(const bf16x8*)&pls[(w * 16 + m16) * 40 + quad * 8];
#pragma unroll
    for (int t = 0; t < 4; ++t) {
      bf16x8 A = *(const bf16x8*)&bgn[(ks * 64 + 16 * t + m16) * 40 + quad * 8];
      O[t] = __builtin_amdgcn_mfma_f32_16x16x32_bf16(A, Pf, O[t], 0, 0, 0);
    }
  }

  // ---- merge the 4 K-splits via LDS (alias staging area) ----
  __syncthreads();
  float* mO = (float*)smem;               // [8w][64c][16q]
  float* mM = (float*)(smem + 32768);     // [8w][16q]
  float* mL = (float*)(smem + 33280);     // [8w][16q]
  if (quad == 0) { mM[w * 16 + m16] = m_run; mL[w * 16 + m16] = l_run; }
#pragma unroll
  for (int t = 0; t < 4; ++t)
#pragma unroll
    for (int r = 0; r < 4; ++r)
      mO[(w * 64 + 16 * t + quad * 4 + r) * 16 + m16] = O[t][r];
  __syncthreads();

  {
    int q32 = tid & 31, ci = tid >> 5;    // ci 0..15 -> c = 4ci..4ci+3
    int qg2 = q32 >> 4, qL = q32 & 15;
    float mw[4], lw[4], M = -1e30f;
#pragma unroll
    for (int s2 = 0; s2 < 4; ++s2) {
      mw[s2] = mM[(s2 * 2 + qg2) * 16 + qL];
      lw[s2] = mL[(s2 * 2 + qg2) * 16 + qL];
      M = fmaxf(M, mw[s2]);
    }
    float L = 0.f, sc[4];
#pragma unroll
    for (int s2 = 0; s2 < 4; ++s2) { sc[s2] = __expf(mw[s2] - M); L += lw[s2] * sc[s2]; }
    float invL = 1.0f / L;
    float maskv = mask[b * HWN + q0 + q32];
#pragma unroll
    for (int e = 0; e < 4; ++e) {
      int c = 4 * ci + e;
      float att = 0.f;
#pragma unroll
      for (int s2 = 0; s2 < 4; ++s2)
        att += mO[((s2 * 2 + qg2) * 64 + c) * 16 + qL] * sc[s2];
      att *= invL;
      float fgv = fgB[(size_t)c * HWN + q0 + q32];
      out[(size_t)b * CC * HWN + (size_t)c * HWN + q0 + q32] = fgv + maskv * (att - fgv);
    }
  }
}

extern "C" void kernel_launch(void* const* d_in, const int* in_sizes, int n_in,
                              void* d_out, int out_size, void* d_ws, size_t ws_size,
                              hipStream_t stream) {
  const float* background = (const float*)d_in[0];
  const float* foreground = (const float*)d_in[1];
  const float* mask       = (const float*)d_in[2];
  float* out = (float*)d_out;
  float* sb = (float*)d_ws;            // [4][4096]
  float* sf = sb + 4 * HWN;            // [4][4096]
  norms_kernel<<<256, 128, 0, stream>>>(background, foreground, sb, sf);
  attn_kernel<<<dim3(HWN / QB, 4), 512, 0, stream>>>(background, foreground, mask, sb, sf, out);
}

// Round 3
// 117.207 us; speedup vs baseline: 3.5106x; 1.3070x over previous
//
#include <hip/hip_runtime.h>
#include <math.h>

#define CC 64
#define HWN 4096
#define QB 64            // q per block = 2 wave-groups x 32
#define KSPLIT 4
#define KT 32
#define NCH (HWN / KSPLIT / KT)   // 32 chunks per wave

typedef __attribute__((ext_vector_type(8))) short bf16x8;
typedef __attribute__((ext_vector_type(4))) float f32x4;

// precomputed bf16 operand layouts (written by prep_kernel every launch)
__device__ __align__(16) unsigned short g_bgT[4][HWN][CC];  // (bg*sb)^T  [b][k][c]
__device__ __align__(16) unsigned short g_bgN[4][CC][HWN];  // bf16(bg)   [b][c][k]
__device__ __align__(16) unsigned short g_fgT[4][HWN][CC];  // (fg*sf)^T  [b][q][c]

static __device__ __forceinline__ unsigned int f2bf(float x) {   // RNE
  union { float f; unsigned int u; } v; v.f = x;
  return (v.u + 0x7fffu + ((v.u >> 16) & 1u)) >> 16;
}
static __device__ __forceinline__ unsigned int packbf(float lo, float hi) {
  return f2bf(lo) | (f2bf(hi) << 16);
}

// ---- prep: fused column norms + bf16 operand layouts ----
// grid 512 = which(2) x b(4) x ktile(64), 256 threads
__global__ __launch_bounds__(256) void prep_kernel(const float* __restrict__ bg,
                                                   const float* __restrict__ fg) {
  __shared__ float lds[64 * 65];   // [k][c], stride 65 (2-way banks everywhere)
  const int bid = blockIdx.x;
  const int kt = bid & 63, b = (bid >> 6) & 3, which = bid >> 8;
  const float* src = (which ? fg : bg) + (size_t)b * CC * HWN + kt * 64;
  const int tid = threadIdx.x;

  // stage tile transposed: thread loads [c][k-range] float4, writes lds[k][c]
  {
    int c = tid >> 2, k0 = (tid & 3) * 16;
#pragma unroll
    for (int j4 = 0; j4 < 4; ++j4) {
      float4 v = *(const float4*)(src + (size_t)c * HWN + k0 + 4 * j4);
      lds[(k0 + 4 * j4 + 0) * 65 + c] = v.x;
      lds[(k0 + 4 * j4 + 1) * 65 + c] = v.y;
      lds[(k0 + 4 * j4 + 2) * 65 + c] = v.z;
      lds[(k0 + 4 * j4 + 3) * 65 + c] = v.w;
    }
  }
  __syncthreads();

  const int k = tid >> 2, u = tid & 3;
  // column norm: 4 threads per k, each sums 16 c, combine via shfl
  float ss = 0.f;
#pragma unroll
  for (int j = 0; j < 16; ++j) {
    float v = lds[k * 65 + u * 16 + j];
    ss = fmaf(v, v, ss);
  }
  ss += __shfl_xor(ss, 1, 64);
  ss += __shfl_xor(ss, 2, 64);
  const float s = 1.0f / fmaxf(sqrtf(ss), 1e-12f);

  // write scaled transposed [b][k][c] bf16
  {
    unsigned int* gT32 = (unsigned int*)(which ? &g_fgT[0][0][0] : &g_bgT[0][0][0]);
    size_t R = (size_t)b * HWN + kt * 64 + k;
    unsigned int w8[8];
#pragma unroll
    for (int i = 0; i < 8; ++i) {
      int c2 = u * 16 + 2 * i;
      w8[i] = packbf(lds[k * 65 + c2] * s, lds[k * 65 + c2 + 1] * s);
    }
    *(uint4*)&gT32[R * 32 + u * 8]     = make_uint4(w8[0], w8[1], w8[2], w8[3]);
    *(uint4*)&gT32[R * 32 + u * 8 + 4] = make_uint4(w8[4], w8[5], w8[6], w8[7]);
  }

  // bg blocks also write raw cast [b][c][k] bf16
  if (which == 0) {
    unsigned int* gN32 = (unsigned int*)&g_bgN[0][0][0];
    int cN = tid >> 2, vN = tid & 3;
    unsigned int n8[8];
#pragma unroll
    for (int i = 0; i < 8; ++i) {
      int kk = vN * 16 + 2 * i;
      n8[i] = packbf(lds[kk * 65 + cN], lds[(kk + 1) * 65 + cN]);
    }
    size_t RN = ((size_t)b * CC + cN) * (HWN / 2) + kt * 32 + vN * 8;
    *(uint4*)&gN32[RN]     = make_uint4(n8[0], n8[1], n8[2], n8[3]);
    *(uint4*)&gN32[RN + 4] = make_uint4(n8[4], n8[5], n8[6], n8[7]);
  }
}

// ---- flash attention: bf16 MFMA, fixed-max softmax, swizzled async staging ----
// LDS: [0,32768) staging (ks*8192: bgT 4KB + bgN 4KB, swizzled)
//      [32768,53248) P per wave [32q][40k] ushort
//      [53248,54272) mL [8w][32q] f32
//      merge aliases [0,34816) as mO [4ks][64c][34]
#define SMEM_BYTES 54272
__global__ __launch_bounds__(512, 2) void attn_kernel(const float* __restrict__ fg,
                                                      const float* __restrict__ mask,
                                                      float* __restrict__ out) {
  __shared__ __align__(16) char smem[SMEM_BYTES];
  const int b = blockIdx.y;
  const int q0 = blockIdx.x * QB;
  const int tid = threadIdx.x;
  const int lane = tid & 63;
  const int w = tid >> 6;     // 0..7
  const int qg = w & 1;       // q-half (32 q)
  const int ks = w >> 1;      // K-split 0..3 (1024 k each)
  const int m16 = lane & 15;
  const int quad = lane >> 4;

  // fg B-fragments, loaded once from global (L2)
  bf16x8 Bf[2][2];
  {
    int qrow = q0 + qg * 32;
#pragma unroll
    for (int qf = 0; qf < 2; ++qf)
#pragma unroll
      for (int h = 0; h < 2; ++h)
        Bf[qf][h] = *(const bf16x8*)&g_fgT[b][qrow + qf * 16 + m16][h * 32 + quad * 8];
  }

  // lane-swizzled staging sources (swizzle on global side; LDS side is lane-ordered)
  const unsigned short* srcT[2];
  const unsigned short* srcN[2];
  char* dstT[2];
  char* dstN[2];
#pragma unroll
  for (int t = 0; t < 2; ++t) {
    int ub = (t * 2 + qg) * 64;
    int uT = ub + lane;
    int kk = uT >> 3, pos = uT & 7, j = pos ^ (kk & 7);
    srcT[t] = &g_bgT[b][ks * 1024 + kk][j * 8];
    dstT[t] = smem + ks * 8192 + ub * 16;
    int uN = ub + lane;
    int cc = uN >> 2, pos4 = uN & 3, j4 = pos4 ^ ((cc >> 1) & 3);
    srcN[t] = &g_bgN[b][cc][ks * 1024 + j4 * 8];
    dstN[t] = smem + ks * 8192 + 4096 + ub * 16;
  }

  unsigned short* P = (unsigned short*)(smem + 32768 + w * 2560);  // [32 q][40 k]
  float* mL = (float*)(smem + 53248);

  float l_run[2] = {0.f, 0.f};
  f32x4 O[4][2];
#pragma unroll
  for (int t = 0; t < 4; ++t)
#pragma unroll
    for (int qf = 0; qf < 2; ++qf) O[t][qf] = (f32x4){0.f, 0.f, 0.f, 0.f};

  const int posN = quad ^ ((m16 >> 1) & 3);
  const char* baseT = smem + ks * 8192;
  const char* baseN = smem + ks * 8192 + 4096;

  for (int it = 0; it < NCH; ++it) {
    __syncthreads();   // previous chunk's LDS reads complete
#pragma unroll
    for (int t = 0; t < 2; ++t) {
      __builtin_amdgcn_global_load_lds(
          (const __attribute__((address_space(1))) unsigned int*)srcT[t],
          (__attribute__((address_space(3))) unsigned int*)dstT[t], 16, 0, 0);
      __builtin_amdgcn_global_load_lds(
          (const __attribute__((address_space(1))) unsigned int*)srcN[t],
          (__attribute__((address_space(3))) unsigned int*)dstN[t], 16, 0, 0);
      srcT[t] += KT * CC;   // next chunk
      srcN[t] += KT;
    }
    __syncthreads();   // staging visible

    // scores S[32k][32q] = (bg*sb)^T · (fg*sf)
    f32x4 S[2][2];
#pragma unroll
    for (int i = 0; i < 2; ++i) {
      int kk = 16 * i + m16;
      bf16x8 A0 = *(const bf16x8*)(baseT + kk * 128 + ((quad) ^ (kk & 7)) * 16);
      bf16x8 A1 = *(const bf16x8*)(baseT + kk * 128 + ((4 + quad) ^ (kk & 7)) * 16);
#pragma unroll
      for (int qf = 0; qf < 2; ++qf) {
        f32x4 acc = {0.f, 0.f, 0.f, 0.f};
        acc = __builtin_amdgcn_mfma_f32_16x16x32_bf16(A0, Bf[qf][0], acc, 0, 0, 0);
        acc = __builtin_amdgcn_mfma_f32_16x16x32_bf16(A1, Bf[qf][1], acc, 0, 0, 0);
        S[qf][i] = acc;
      }
    }

    // fixed-max softmax: scores are cosines, |s| <= 1 -> p = exp(s-1), no running max
#pragma unroll
    for (int qf = 0; qf < 2; ++qf) {
      float pe[2][4];
      float ps = 0.f;
#pragma unroll
      for (int i = 0; i < 2; ++i)
#pragma unroll
        for (int r = 0; r < 4; ++r) {
          pe[i][r] = __expf(S[qf][i][r] - 1.0f);
          ps += pe[i][r];
        }
      ps += __shfl_xor(ps, 16, 64);
      ps += __shfl_xor(ps, 32, 64);
      l_run[qf] += ps;
      // pack P -> per-wave LDS [q][k] bf16 (round-half-up via +0x8000, v_perm pack)
#pragma unroll
      for (int i = 0; i < 2; ++i) {
        union { float f; unsigned int u; } x0, x1, x2, x3;
        x0.f = pe[i][0]; x1.f = pe[i][1]; x2.f = pe[i][2]; x3.f = pe[i][3];
        unsigned int p01 = __builtin_amdgcn_perm(x1.u + 0x8000u, x0.u + 0x8000u, 0x07060302u);
        unsigned int p23 = __builtin_amdgcn_perm(x3.u + 0x8000u, x2.u + 0x8000u, 0x07060302u);
        *(uint2*)&P[(qf * 16 + m16) * 40 + 16 * i + quad * 4] = make_uint2(p01, p23);
      }
    }

    // PV: O[c][q] += bg[c][k] · P[k][q]   (per-wave P: no barrier needed)
    bf16x8 Pf0 = *(const bf16x8*)&P[m16 * 40 + quad * 8];
    bf16x8 Pf1 = *(const bf16x8*)&P[(16 + m16) * 40 + quad * 8];
#pragma unroll
    for (int t = 0; t < 4; ++t) {
      int c = 16 * t + m16;
      bf16x8 A = *(const bf16x8*)(baseN + c * 64 + posN * 16);
      O[t][0] = __builtin_amdgcn_mfma_f32_16x16x32_bf16(A, Pf0, O[t][0], 0, 0, 0);
      O[t][1] = __builtin_amdgcn_mfma_f32_16x16x32_bf16(A, Pf1, O[t][1], 0, 0, 0);
    }
  }

  // ---- merge 4 K-splits + epilogue (two q-half passes; mO aliases staging LDS) ----
  if (quad == 0) {
    mL[w * 32 + m16] = l_run[0];
    mL[w * 32 + 16 + m16] = l_run[1];
  }
  float* mO = (float*)smem;   // [4 ks][64 c][34]
  const float* fgB = fg + (size_t)b * CC * HWN;
  const float* mk = mask + (size_t)b * HWN;
  float* outB = out + (size_t)b * CC * HWN;

#pragma unroll
  for (int half = 0; half < 2; ++half) {
    __syncthreads();
    if (qg == half) {
#pragma unroll
      for (int t = 0; t < 4; ++t)
#pragma unroll
        for (int qf = 0; qf < 2; ++qf)
#pragma unroll
          for (int r = 0; r < 4; ++r)
            mO[(ks * 64 + 16 * t + quad * 4 + r) * 34 + qf * 16 + m16] = O[t][qf][r];
    }
    __syncthreads();
    {
      int q = tid & 31, cb = tid >> 5;   // cb 0..15
      int qglob = q0 + half * 32 + q;
      float L = mL[(0 * 2 + half) * 32 + q] + mL[(1 * 2 + half) * 32 + q] +
                mL[(2 * 2 + half) * 32 + q] + mL[(3 * 2 + half) * 32 + q];
      float invL = 1.0f / L;
      float mv = mk[qglob];
#pragma unroll
      for (int e = 0; e < 4; ++e) {
        int c = cb * 4 + e;
        float acc = mO[(0 * 64 + c) * 34 + q] + mO[(1 * 64 + c) * 34 + q] +
                    mO[(2 * 64 + c) * 34 + q] + mO[(3 * 64 + c) * 34 + q];
        float att = acc * invL;
        float fgv = fgB[(size_t)c * HWN + qglob];
        outB[(size_t)c * HWN + qglob] = fgv + mv * (att - fgv);
      }
    }
  }
}

extern "C" void kernel_launch(void* const* d_in, const int* in_sizes, int n_in,
                              void* d_out, int out_size, void* d_ws, size_t ws_size,
                              hipStream_t stream) {
  const float* background = (const float*)d_in[0];
  const float* foreground = (const float*)d_in[1];
  const float* mask       = (const float*)d_in[2];
  float* out = (float*)d_out;
  prep_kernel<<<512, 256, 0, stream>>>(background, foreground);
  attn_kernel<<<dim3(HWN / QB, 4), 512, 0, stream>>>(foreground, mask, out);
}